// Round 15
// baseline (409.488 us; speedup 1.0000x reference)
//
#include <hip/hip_runtime.h>
#include <hip/hip_bf16.h>
#include <stdint.h>

// Problem constants (reference: LoRA adapter forward)
#define TOKENS   8192
#define DIM      4096
#define DIM_OUT  4096
#define LORA_R   16
#define LORA_SCALE 2.0f

typedef __bf16 bf16_t;
typedef __attribute__((ext_vector_type(8))) __bf16 bfrag;   // 8 bf16 = 4 VGPR (MFMA A/B frag)
typedef __attribute__((ext_vector_type(4))) float f32x4;    // MFMA C/D frag

// ---------------------------------------------------------------------------
// async global->LDS, 16B per lane (global_load_lds_dwordx4)
// ---------------------------------------------------------------------------
__device__ __forceinline__ void gload_lds16(const bf16_t* gsrc, bf16_t* ldst) {
    __builtin_amdgcn_global_load_lds(
        (const __attribute__((address_space(1))) uint32_t*)(const void*)gsrc,
        (__attribute__((address_space(3))) uint32_t*)(void*)ldst,
        16, 0, 0);
}

// ---------------------------------------------------------------------------
// Kernel 1: weff only (cast kernel eliminated -- gemm reads x directly).
// Weff_t[n][k] = W[n][k] + SCALE*sum_r A[k][r]B[r][n]  (R3-validated body)
// ---------------------------------------------------------------------------
__global__ void weff_kernel(const float* __restrict__ W, const float* __restrict__ A,
                            const float* __restrict__ B, bf16_t* __restrict__ Wt) {
    int idx = blockIdx.x * blockDim.x + threadIdx.x;   // DIM_OUT*DIM/32 threads
    int k0 = (idx & 511) << 3;          // 512 k-groups of 8
    int n0 = (idx >> 9) << 2;           // 1024 n-groups of 4

    float bn[4][16];
#pragma unroll
    for (int r = 0; r < 16; ++r) {
        float4 bv = *reinterpret_cast<const float4*>(B + (size_t)r * DIM_OUT + n0);
        bn[0][r] = bv.x; bn[1][r] = bv.y; bn[2][r] = bv.z; bn[3][r] = bv.w;
    }
    float ab[4][8];
#pragma unroll
    for (int j = 0; j < 8; ++j) {
        const float4* ap = reinterpret_cast<const float4*>(A + (size_t)(k0 + j) * LORA_R);
        float4 a0 = ap[0], a1 = ap[1], a2 = ap[2], a3 = ap[3];
        float av[16] = {a0.x,a0.y,a0.z,a0.w,a1.x,a1.y,a1.z,a1.w,
                        a2.x,a2.y,a2.z,a2.w,a3.x,a3.y,a3.z,a3.w};
#pragma unroll
        for (int n = 0; n < 4; ++n) {
            float s = 0.f;
#pragma unroll
            for (int r = 0; r < 16; ++r) s += av[r] * bn[n][r];
            ab[n][j] = s;
        }
    }
#pragma unroll
    for (int n = 0; n < 4; ++n) {
        const float4* wp = reinterpret_cast<const float4*>(W + (size_t)(n0 + n) * DIM + k0);
        float4 w0 = wp[0], w1 = wp[1];
        float wv[8] = {w0.x,w0.y,w0.z,w0.w,w1.x,w1.y,w1.z,w1.w};
        union { bf16_t o[8]; uint4 u; } pk;
#pragma unroll
        for (int j = 0; j < 8; ++j) pk.o[j] = (bf16_t)(wv[j] + LORA_SCALE * ab[n][j]);
        *reinterpret_cast<uint4*>(Wt + (size_t)(n0 + n) * DIM + k0) = pk.u;
    }
}

// ---------------------------------------------------------------------------
// Kernel 2: 256x256 GEMM, R12 8-phase + XCD mapping; A staged from x (fp32)
// via reg-path: LOADX2 (8x global_load_dwordx4 into TWO NAMED SETS xa/xb) at
// P1/P5; WRITEX_A (cvt+2 ds_write_b128, h0) at P2/P6; WRITEX_B (h1) at P3/P7.
// R13's bug (single xf set overwritten before consumption) fixed by the
// two-set naming.  B staging keeps the proven gload_lds path.
//
// Phase slots (iter reads u=2j (d0), v=u+1 (d1)):
//   P1: ds a0-3,b0-1(d0); LOADX2 A(v)            | MFMA m0-3 x n0-1
//   P2: ds b2-3(d0); WRITEX_A->d1                | MFMA m0-3 x n2-3
//   P3: ds a4-7(d0); WRITEX_B->d1; glB(u+2)H0    | MFMA m4-7 x n2-3
//   P4: glB(u+2)H1                               | MFMA m4-7 x n0-1; vm(4)
//   P5: ds a0-3,b0-1(d1); LOADX2 A(u+2)          | MFMA m0-3 x n0-1
//   P6: ds b2-3(d1); WRITEX_A->d0                | MFMA m0-3 x n2-3
//   P7: ds a4-7(d1); WRITEX_B->d0; glB(v+2)H0    | MFMA m4-7 x n2-3
//   P8: glB(v+2)H1                               | MFMA m4-7 x n0-1; vm(4)
// Implicit-vmcnt ledger: P2's WRITEX_A wait = vmcnt(4) (xb newer) ->
// retires B(v)'s 4 gloads (prev iter) 3 phases before P5 reads them;
// P6's wait retires B(u+2) before next-iter P1.  Queue never drains while
// B loads younger than 2 phases are in flight (T4 for the B path).
// WAR: every sA/sB region's readers lgkm-retired >=3 barriers before its
// overwrite (same windows as R12, verified per slot).
// ---------------------------------------------------------------------------
#define BM 256
#define BN 256
#define BK 64
#define MB_BLKS (TOKENS / BM)    // 32
#define NB_BLKS (DIM_OUT / BN)   // 16
#define NT      (DIM / BK)       // 64 K-tiles

#define SB0() __builtin_amdgcn_sched_barrier(0)
#define VMWAIT_(n) asm volatile("s_waitcnt vmcnt(" #n ")" ::: "memory")
#define VMWAIT(n) VMWAIT_(n)

__global__ __launch_bounds__(512, 2) void gemm_kernel(
    const float* __restrict__ X, const bf16_t* __restrict__ Wt,
    const float* __restrict__ bias, float* __restrict__ C)
{
    __shared__ __align__(16) bf16_t sA[2][BM][BK];   // 64 KiB
    __shared__ __align__(16) bf16_t sB[2][BN][BK];   // 64 KiB

    // ---- XCD-local 2-D mapping (R11-validated: FETCH -33%) ----
    int bid = blockIdx.x;
    int xcd = bid & 7;
    int j   = bid >> 3;              // 0..63 within XCD
    int qq  = j >> 5;                // 0..1
    int rr  = j & 31;                // 0..31
    int bm  = xcd * 4 + (rr >> 3);   // 0..31
    int bn  = (rr & 7) + 8 * qq;     // 0..15

    const int tid  = threadIdx.x;
    const int lane = tid & 63;
    const int wid  = tid >> 6;       // 0..7
    const int wr   = wid >> 2;       // 0..1  (M half: 128 rows)
    const int wc   = wid & 3;        // 0..3  (N quarter: 64 cols)

    // ---- staging constants (linear LDS dest, pre-swizzled global src) ----
    const int srow = tid >> 3;                       // 0..63
    const int scol = (tid & 7) * 8;                  // linear col (elems)
    const int koff = (((tid & 7) ^ ((tid >> 3) & 7)) * 8); // swizzled src col
    const float*  Xg = X  + (size_t)(bm * BM + srow) * DIM + koff;
    const bf16_t* Bg = Wt + (size_t)(bn * BN + srow) * DIM + koff;

    // A reg-staging: TWO named sets (h0 -> xa, h1 -> xb); rule-#20 safe.
    float4 xa0, xa1, xa2, xa3, xb0, xb1, xb2, xb3;
#define LOADX2(kt) do { \
    const float* s0_ = Xg + (size_t)(kt) * BK; \
    const float* s1_ = s0_ + (size_t)128 * DIM; \
    xa0 = *reinterpret_cast<const float4*>(s0_); \
    xa1 = *reinterpret_cast<const float4*>(s0_ + 4); \
    xa2 = *reinterpret_cast<const float4*>(s0_ + (size_t)64 * DIM); \
    xa3 = *reinterpret_cast<const float4*>(s0_ + (size_t)64 * DIM + 4); \
    xb0 = *reinterpret_cast<const float4*>(s1_); \
    xb1 = *reinterpret_cast<const float4*>(s1_ + 4); \
    xb2 = *reinterpret_cast<const float4*>(s1_ + (size_t)64 * DIM); \
    xb3 = *reinterpret_cast<const float4*>(s1_ + (size_t)64 * DIM + 4); \
} while (0)

#define CVT8(u_, f0, f1) do { \
    u_.o[0] = (bf16_t)f0.x; u_.o[1] = (bf16_t)f0.y; \
    u_.o[2] = (bf16_t)f0.z; u_.o[3] = (bf16_t)f0.w; \
    u_.o[4] = (bf16_t)f1.x; u_.o[5] = (bf16_t)f1.y; \
    u_.o[6] = (bf16_t)f1.z; u_.o[7] = (bf16_t)f1.w; \
} while (0)

#define WRITEX_A(dd) do { \
    union { bf16_t o[8]; uint4 u; } p0_, p1_; \
    CVT8(p0_, xa0, xa1); CVT8(p1_, xa2, xa3); \
    *reinterpret_cast<uint4*>(&sA[dd][srow][scol]) = p0_.u; \
    *reinterpret_cast<uint4*>(&sA[dd][64 + srow][scol]) = p1_.u; \
} while (0)

#define WRITEX_B(dd) do { \
    union { bf16_t o[8]; uint4 u; } p0_, p1_; \
    CVT8(p0_, xb0, xb1); CVT8(p1_, xb2, xb3); \
    *reinterpret_cast<uint4*>(&sA[dd][128 + srow][scol]) = p0_.u; \
    *reinterpret_cast<uint4*>(&sA[dd][192 + srow][scol]) = p1_.u; \
} while (0)

#define STAGE_B_H(dd, kt, h) do { \
    const bf16_t* s_ = Bg + (size_t)(kt) * BK + (size_t)((h) * 128) * DIM; \
    bf16_t* d_ = &sB[dd][(h) * 128 + srow][scol]; \
    gload_lds16(s_,                    d_); \
    gload_lds16(s_ + (size_t)64 * DIM, d_ + 64 * BK); \
} while (0)

    // ---- fragment-read constants (swizzled, 0 conflicts R1-R12) ----
    const int q     = lane & 7;
    const int kslot = lane >> 4;                     // 0..3
    const int r15   = lane & 15;
    const int cK0   = ((kslot    ) ^ q) * 8;         // ks=0 col (elems)
    const int cK1   = ((kslot + 4) ^ q) * 8;         // ks=1 col (elems)
    const int arow0 = wr * 128 + r15;                // + m*16
    const int brow0 = wc * 64  + r15;                // + n*16

    f32x4 acc[8][4] = {};
    bfrag a[4][2], bLo[2][2], bHi[2][2];

#define READ_A4(dd, mb) do { \
    _Pragma("unroll") \
    for (int m_ = 0; m_ < 4; ++m_) { \
        a[m_][0] = *reinterpret_cast<const bfrag*>(&sA[dd][arow0 + (mb + m_) * 16][cK0]); \
        a[m_][1] = *reinterpret_cast<const bfrag*>(&sA[dd][arow0 + (mb + m_) * 16][cK1]); \
    } \
} while (0)

#define READ_B2(dst, dd, nb) do { \
    _Pragma("unroll") \
    for (int n_ = 0; n_ < 2; ++n_) { \
        dst[n_][0] = *reinterpret_cast<const bfrag*>(&sB[dd][brow0 + (nb + n_) * 16][cK0]); \
        dst[n_][1] = *reinterpret_cast<const bfrag*>(&sB[dd][brow0 + (nb + n_) * 16][cK1]); \
    } \
} while (0)

// phase sync: barrier, then wait this phase's ds ops (reads AND writes)
#define PSYNC() do { \
    __builtin_amdgcn_s_barrier(); \
    asm volatile("s_waitcnt lgkmcnt(0)" ::: "memory"); \
    SB0(); \
} while (0)

#define MFMA_Q(Bf, mb, nb) do { \
    __builtin_amdgcn_s_setprio(1); \
    _Pragma("unroll") \
    for (int m_ = 0; m_ < 4; ++m_) \
    _Pragma("unroll") \
    for (int n_ = 0; n_ < 2; ++n_) \
    _Pragma("unroll") \
    for (int ks_ = 0; ks_ < 2; ++ks_) \
        acc[mb + m_][nb + n_] = __builtin_amdgcn_mfma_f32_16x16x32_bf16( \
            a[m_][ks_], Bf[n_][ks_], acc[mb + m_][nb + n_], 0, 0, 0); \
    __builtin_amdgcn_s_setprio(0); \
} while (0)

#define EBAR() __builtin_amdgcn_s_barrier()

    // ---- prologue: A(0)->d0 via reg-path; B(0)->d0, B(1)->d1 gload ----
    LOADX2(0);
    WRITEX_A(0);        // waits xa (vmcnt(4): xb newer)
    WRITEX_B(0);        // waits xb
    STAGE_B_H(0, 0, 0); STAGE_B_H(0, 0, 1);
    STAGE_B_H(1, 1, 0); STAGE_B_H(1, 1, 1);
    VMWAIT(4);          // B(0) landed; B(1)'s 4 stay in flight
    asm volatile("s_waitcnt lgkmcnt(0)" ::: "memory");  // A(0) ds_writes done
    EBAR();

    // ---- main loop: iters 0..30 read (2j,2j+1) ----
    for (int it = 0; it < NT / 2 - 1; ++it) {
        int u = 2 * it;
        /* P1 */ READ_A4(0, 0); READ_B2(bLo, 0, 0); LOADX2(u + 1);
                 PSYNC(); MFMA_Q(bLo, 0, 0); EBAR();
        /* P2 */ READ_B2(bHi, 0, 2); WRITEX_A(1);
                 PSYNC(); MFMA_Q(bHi, 0, 2); EBAR();
        /* P3 */ READ_A4(0, 4); WRITEX_B(1); STAGE_B_H(0, u + 2, 0);
                 PSYNC(); MFMA_Q(bHi, 4, 2); EBAR();
        /* P4 */ STAGE_B_H(0, u + 2, 1);
                 __builtin_amdgcn_s_barrier();
                 MFMA_Q(bLo, 4, 0); VMWAIT(4); EBAR();
        /* P5 */ READ_A4(1, 0); READ_B2(bLo, 1, 0); LOADX2(u + 2);
                 PSYNC(); MFMA_Q(bLo, 0, 0); EBAR();
        /* P6 */ READ_B2(bHi, 1, 2); WRITEX_A(0);
                 PSYNC(); MFMA_Q(bHi, 0, 2); EBAR();
        /* P7 */ READ_A4(1, 4); WRITEX_B(0); STAGE_B_H(1, u + 3, 0);
                 PSYNC(); MFMA_Q(bHi, 4, 2); EBAR();
        /* P8 */ STAGE_B_H(1, u + 3, 1);
                 __builtin_amdgcn_s_barrier();
                 MFMA_Q(bLo, 4, 0); VMWAIT(4); EBAR();
    }
    // ---- last iter (tiles 62,63): stages only A(63); drain at P4 ----
    /* P1 */ READ_A4(0, 0); READ_B2(bLo, 0, 0); LOADX2(63);
             PSYNC(); MFMA_Q(bLo, 0, 0); EBAR();
    /* P2 */ READ_B2(bHi, 0, 2); WRITEX_A(1);
             PSYNC(); MFMA_Q(bHi, 0, 2); EBAR();
    /* P3 */ READ_A4(0, 4); WRITEX_B(1);
             PSYNC(); MFMA_Q(bHi, 4, 2); EBAR();
    /* P4 */ __builtin_amdgcn_s_barrier();
             MFMA_Q(bLo, 4, 0); VMWAIT(0); EBAR();   // all B loads landed
    /* P5 */ READ_A4(1, 0); READ_B2(bLo, 1, 0);
             PSYNC(); MFMA_Q(bLo, 0, 0); EBAR();
    /* P6 */ READ_B2(bHi, 1, 2);
             PSYNC(); MFMA_Q(bHi, 0, 2); EBAR();
    /* P7 */ READ_A4(1, 4);
             PSYNC(); MFMA_Q(bHi, 4, 2); EBAR();
    /* P8 */ MFMA_Q(bLo, 4, 0);

    // ---- epilogue: D layout row=(lane>>4)*4+j, col=lane&15 ----
    int row0 = bm * BM + wr * 128 + (lane >> 4) * 4;
    int col0 = bn * BN + wc * 64 + r15;
#pragma unroll
    for (int n = 0; n < 4; ++n) {
        int c = col0 + n * 16;
        float bv = bias[c];
#pragma unroll
        for (int m = 0; m < 8; ++m) {
            int r = row0 + m * 16;
#pragma unroll
            for (int jj = 0; jj < 4; ++jj)
                C[(size_t)(r + jj) * DIM_OUT + c] = acc[m][n][jj] + bv;
        }
    }
}

// ---------------------------------------------------------------------------
extern "C" void kernel_launch(void* const* d_in, const int* in_sizes, int n_in,
                              void* d_out, int out_size, void* d_ws, size_t ws_size,
                              hipStream_t stream) {
    const float* x = (const float*)d_in[0];
    const float* A = (const float*)d_in[1];
    const float* B = (const float*)d_in[2];
    const float* W = (const float*)d_in[3];
    const float* b = (const float*)d_in[4];
    float* out = (float*)d_out;

    // workspace: Wt (4096*4096 bf16 = 32MB) only -- xb eliminated
    bf16_t* Wt = (bf16_t*)d_ws;

    weff_kernel<<<(DIM_OUT * DIM / 32) / 256, 256, 0, stream>>>(W, A, B, Wt);
    gemm_kernel<<<MB_BLKS * NB_BLKS, 512, 0, stream>>>(x, Wt, b, out);
}